// Round 10
// baseline (99.526 us; speedup 1.0000x reference)
//
#include <hip/hip_runtime.h>
#include <math.h>

#define NN 8192
#define DIM 128
#define NG 512                        // 16-row strips
#define NCT 128                       // 64-col tiles per row
#define NITEMS (NG * 16)              // 8192 (strip, phase) items
#define NBLOCKS1 768
#define NWT (NBLOCKS1 * 4)            // 3072 waves in phase 1
#define NB2 2048                      // phase-2 blocks

typedef short bf16x8 __attribute__((ext_vector_type(8)));
typedef float f32x4 __attribute__((ext_vector_type(4)));

__device__ inline unsigned short f2bf(float x) {
    unsigned u = __float_as_uint(x);
    unsigned r = u + 0x7FFFu + ((u >> 16) & 1u);  // RNE
    return (unsigned short)(r >> 16);
}
__device__ inline float bf2f(unsigned short h) {
    return __uint_as_float(((unsigned)h) << 16);
}

// ---------------------------------------------------------------------------
// Kernel 0: pack mapping into MFMA-fragment-order bf16 chunks (1KB/wave-load).
// ---------------------------------------------------------------------------
__global__ void pack_kernel(const float* __restrict__ m, unsigned short* __restrict__ buf2) {
    const int t = threadIdx.x, l = t & 63;
    const int W = blockIdx.x * 4 + (t >> 6);
    const int g = W >> 2, kq = W & 3;
    const int row = g * 16 + (l & 15);
    const int k0 = kq * 32 + (l >> 4) * 8;
    const float* src = m + (size_t)row * DIM + k0;
    float4 v0 = *reinterpret_cast<const float4*>(src);
    float4 v1 = *reinterpret_cast<const float4*>(src + 4);
    float f[8] = {v0.x, v0.y, v0.z, v0.w, v1.x, v1.y, v1.z, v1.w};
    union { ushort4 u4[2]; unsigned short us[8]; } o;
#pragma unroll
    for (int q = 0; q < 8; ++q) o.us[q] = f2bf(f[q]);
    unsigned short* dst = buf2 + (size_t)W * 512 + l * 8;
    *reinterpret_cast<ushort4*>(dst) = o.u4[0];
    *reinterpret_cast<ushort4*>(dst + 4) = o.u4[1];
}

// ---------------------------------------------------------------------------
// Kernel 1: exact fp32 row norms
// ---------------------------------------------------------------------------
__global__ void sq_kernel(const float* __restrict__ mapping, float* __restrict__ sq) {
    int i = blockIdx.x * blockDim.x + threadIdx.x;
    if (i < NN) {
        const float4* row = reinterpret_cast<const float4*>(mapping + (size_t)i * DIM);
        float s = 0.f;
#pragma unroll
        for (int q = 0; q < DIM / 4; ++q) {
            float4 v = row[q];
            s += v.x * v.x + v.y * v.y + v.z * v.z + v.w * v.w;
        }
        sq[i] = s;
    }
}

// ---------------------------------------------------------------------------
// Kernel 2 (PHASE 1): compute d(i,j) = sqrt(max(sa+sb-2*G,0)) for the upper
// triangle (by 64-col tiles from each strip's diagonal tile), store bf16 to
// dbuf[i][j]. No D traffic at all: L2-resident operands + MFMA + writes.
// ---------------------------------------------------------------------------
__global__ __launch_bounds__(256, 3) void dcomp_kernel(const unsigned short* __restrict__ buf2,
                                                       const float* __restrict__ sq,
                                                       unsigned short* __restrict__ dbuf) {
    const int t = threadIdx.x, l = t & 63;
    const int W = blockIdx.x * 4 + (t >> 6);
    const int l15 = l & 15;
    const int colq = (l >> 4) * 4;

    for (int item = W; item < NITEMS; item += NWT) {
        const int g = item >> 4, p = item & 15;
        int cj = (g >> 2) + p;
        if (cj >= NCT) continue;

        const int i_row = g * 16 + l15;

        bf16x8 af[4];
#pragma unroll
        for (int kq = 0; kq < 4; ++kq)
            af[kq] = *(const bf16x8*)(buf2 + (size_t)(g * 4 + kq) * 512 + l * 8);
        const float sa = sq[i_row];

        for (; cj < NCT; cj += 16) {
            bf16x8 bfr[4][4];
#pragma unroll
            for (int s = 0; s < 4; ++s)
#pragma unroll
                for (int kq = 0; kq < 4; ++kq)
                    bfr[s][kq] = *(const bf16x8*)(buf2 + (size_t)((cj * 4 + s) * 4 + kq) * 512 + l * 8);

#pragma unroll
            for (int s = 0; s < 4; ++s) {
                const int jc = cj * 64 + s * 16 + colq;
                f32x4 sb = *reinterpret_cast<const f32x4*>(sq + jc);
                f32x4 acc = {};
#pragma unroll
                for (int kq = 0; kq < 4; ++kq)
                    acc = __builtin_amdgcn_mfma_f32_16x16x32_bf16(bfr[s][kq], af[kq], acc, 0, 0, 0);
                union { ushort4 u4; unsigned short us[4]; } o;
#pragma unroll
                for (int r = 0; r < 4; ++r) {
                    float d2 = fmaf(-2.f, acc[r], sa + sb[r]);
                    o.us[r] = f2bf(sqrtf(fmaxf(d2, 0.f)));
                }
                *reinterpret_cast<ushort4*>(dbuf + (size_t)i_row * NN + jc) = o.u4;
            }
        }
    }
}

// ---------------------------------------------------------------------------
// Kernel 3 (PHASE 2): pure stream. Read D (f32) + dbuf (bf16) fully
// sequentially per row, accumulate ratios for j > i. Row pairs (i, 8190-i)
// give every block exactly 16384 elements.
// ---------------------------------------------------------------------------
__device__ inline void row_accum(const float* __restrict__ D,
                                 const unsigned short* __restrict__ dbuf,
                                 int i, int t, float& lsum) {
    const int j0 = (i + 1) & ~3;
    const float* Drow = D + (size_t)i * NN;
    const unsigned short* drow = dbuf + (size_t)i * NN;
    for (int j = j0 + t * 4; j < NN; j += 1024) {
        float4 Dv = *reinterpret_cast<const float4*>(Drow + j);
        ushort4 dv = *reinterpret_cast<const ushort4*>(drow + j);
        const float Df[4] = {Dv.x, Dv.y, Dv.z, Dv.w};
        const unsigned short du[4] = {dv.x, dv.y, dv.z, dv.w};
#pragma unroll
        for (int c = 0; c < 4; ++c) {
            float r = __fdividef(fabsf(bf2f(du[c]) - Df[c]), Df[c]);
            lsum += (j + c > i) ? r : 0.f;
        }
    }
}

__global__ __launch_bounds__(256, 8) void stream_kernel(const float* __restrict__ D,
                                                        const unsigned short* __restrict__ dbuf,
                                                        float* __restrict__ partials2) {
    const int t = threadIdx.x, b = blockIdx.x, l = t & 63, w = t >> 6;
    float lsum = 0.f;
    row_accum(D, dbuf, b, t, lsum);
    row_accum(D, dbuf, 8190 - b, t, lsum);
    if (b < 2047) {
        row_accum(D, dbuf, b + 2048, t, lsum);
        row_accum(D, dbuf, 6142 - b, t, lsum);
    }
    if (b == 2047) row_accum(D, dbuf, 4095, t, lsum);

    for (int off = 32; off > 0; off >>= 1) lsum += __shfl_down(lsum, off, 64);
    __shared__ float wsum[4];
    if (l == 0) wsum[w] = lsum;
    __syncthreads();
    if (t == 0) partials2[b] = (wsum[0] + wsum[1]) + (wsum[2] + wsum[3]);
}

// ---------------------------------------------------------------------------
// Kernel 4: deterministic final reduction (upper-tri sum x2)
// ---------------------------------------------------------------------------
__global__ void reduce_kernel(const float* __restrict__ partials2, float* __restrict__ out) {
    __shared__ double sm[256];
    const int t = threadIdx.x;
    double s = 0.0;
    for (int i = t; i < NB2; i += 256) s += (double)partials2[i];
    sm[t] = s;
    __syncthreads();
    for (int off = 128; off > 0; off >>= 1) {
        if (t < off) sm[t] += sm[t + off];
        __syncthreads();
    }
    if (t == 0) out[0] = (float)(2.0 * sm[0] / ((double)NN * (double)NN - (double)NN));
}

// ---------------------------------------------------------------------------
extern "C" void kernel_launch(void* const* d_in, const int* in_sizes, int n_in,
                              void* d_out, int out_size, void* d_ws, size_t ws_size,
                              hipStream_t stream) {
    const float* mapping = (const float*)d_in[0];
    const float* D       = (const float*)d_in[1];
    float* out = (float*)d_out;

    unsigned short* buf2    = (unsigned short*)d_ws;         // NN*DIM bf16 = 2 MiB
    float* sq               = (float*)(buf2 + NN * DIM);     // NN floats
    float* partials2        = sq + NN;                       // NB2 floats
    unsigned short* dbuf    = (unsigned short*)(partials2 + NB2);  // NN*NN bf16 = 128 MiB

    pack_kernel<<<512, 256, 0, stream>>>(mapping, buf2);
    sq_kernel<<<NN / 256, 256, 0, stream>>>(mapping, sq);
    dcomp_kernel<<<NBLOCKS1, 256, 0, stream>>>(buf2, sq, dbuf);
    stream_kernel<<<NB2, 256, 0, stream>>>(D, dbuf, partials2);
    reduce_kernel<<<1, 256, 0, stream>>>(partials2, out);
}